// Round 5
// baseline (134.048 us; speedup 1.0000x reference)
//
#include <hip/hip_runtime.h>

#define Tcnt 32768      // B*S
#define Gn   2
#define Vn   320
#define Dn   128
#define DIMK 512
#define GV   640        // G*V

typedef __attribute__((ext_vector_type(8))) short bf16x8;
typedef __attribute__((ext_vector_type(8))) ushort u16x8;
typedef __attribute__((ext_vector_type(4))) float f32x4;

__device__ inline ushort f2bf(float x) {
    unsigned u = __float_as_uint(x);
    return (ushort)((u + 0x7fffu + ((u >> 16) & 1u)) >> 16);   // RNE
}

#define AS1(p) ((const __attribute__((address_space(1))) void*)(p))
#define AS3(p) ((__attribute__((address_space(3))) void*)(p))

// ---------------- prep: W [512,640] fp32 -> Wt [640,512] bf16 (transposed) ----------
__global__ __launch_bounds__(256) void prep_wt(
    const float* __restrict__ W, ushort* __restrict__ Wt)
{
    __shared__ ushort Ls[64][72];
    int t = blockIdx.x;                     // 0..79
    int n0 = (t % 10) * 64, k0 = (t / 10) * 64;
    int ln = threadIdx.x & 63, kq = threadIdx.x >> 6;
    #pragma unroll
    for (int kk = 0; kk < 16; ++kk) {
        int k = kq * 16 + kk;
        Ls[k][ln] = f2bf(W[(size_t)(k0 + k) * GV + n0 + ln]);
    }
    __syncthreads();
    #pragma unroll
    for (int nn = 0; nn < 16; ++nn) {
        int n = kq * 16 + nn;
        Wt[(size_t)(n0 + n) * DIMK + k0 + ln] = Ls[ln][n];
    }
}

// ------- fused: GEMM(128x320) + bias + softmax + gumbel-argmax(+fixup) + gather ------
__global__ __launch_bounds__(512, 4) void fused_vq_kernel(
    const float*  __restrict__ hs,    // [T, 512] fp32
    const ushort* __restrict__ Wt,    // [640, 512] bf16 transposed
    const float*  __restrict__ W,     // [512, 640] fp32 (fixup only)
    const float*  __restrict__ bias,  // [640]
    const float*  __restrict__ gum,   // [T*G, 320]
    const float*  __restrict__ cv,    // [640, 128]
    float* __restrict__ out,          // [T, 256]
    float* __restrict__ dist)         // [T*G, 320]
{
    __shared__ ushort As[2][128 * 32];    // 8 KB x2
    __shared__ ushort Bs[2][Vn * 32];     // 20 KB x2
    __shared__ float4 part[128][2];       // {mxl, sum, mxs, idx} per half
    __shared__ int    s_cnt[128];
    __shared__ int    s_col[128][8];
    __shared__ float  s_s[128][8];
    __shared__ float  s_gm[128][8];
    __shared__ int    s_bidx[128];
    __shared__ float  s_mxs[128];

    const int tid = threadIdx.x, w = tid >> 6, lane = tid & 63;
    const int Q = lane >> 4, c16 = lane & 15;
    const int wm = (w >> 1) * 32, wn = (w & 1) * 160, half = w & 1;

    const int bid = blockIdx.x;
    const int swz = (bid & 7) * 64 + (bid >> 3);   // XCD chunking (512 % 8 == 0)
    const int g = swz & 1;
    const size_t t0 = (size_t)(swz >> 1) * 128;

    if (tid < 128) s_cnt[tid] = 0;

    // ---- staging maps (rule 21: linear LDS dest, inverse-swizzled source) ----
    const int am = tid >> 2, acp = tid & 3, acl = acp ^ ((am >> 1) & 3);
    const float* asrc = hs + (t0 + am) * DIMK + acl * 8;
    const ushort* wtg = Wt + (size_t)g * Vn * DIMK;

    auto stageB = [&](int buf, int k0) {
        #pragma unroll
        for (int i = 0; i < 2; ++i) {
            int s = i * 512 + tid;
            int n = s >> 2, cp = s & 3, cl = cp ^ ((n >> 1) & 3);
            __builtin_amdgcn_global_load_lds(
                AS1(wtg + (size_t)n * DIMK + k0 + cl * 8),
                AS3(&Bs[buf][s * 8]), 16, 0, 0);
        }
        if (w < 4) {
            int s = 1024 + tid;
            int n = s >> 2, cp = s & 3, cl = cp ^ ((n >> 1) & 3);
            __builtin_amdgcn_global_load_lds(
                AS1(wtg + (size_t)n * DIMK + k0 + cl * 8),
                AS3(&Bs[buf][s * 8]), 16, 0, 0);
        }
    };
    auto writeA = [&](int buf, float4 x, float4 y) {
        u16x8 o;
        o[0]=f2bf(x.x); o[1]=f2bf(x.y); o[2]=f2bf(x.z); o[3]=f2bf(x.w);
        o[4]=f2bf(y.x); o[5]=f2bf(y.y); o[6]=f2bf(y.z); o[7]=f2bf(y.w);
        *(u16x8*)&As[buf][tid * 8] = o;
    };

    // ---- prologue ----
    float4 pa = *(const float4*)(asrc);
    float4 pb = *(const float4*)(asrc + 4);
    stageB(0, 0);
    writeA(0, pa, pb);
    __syncthreads();

    f32x4 acc[20];
    #pragma unroll
    for (int f = 0; f < 20; ++f) acc[f] = (f32x4){0.f, 0.f, 0.f, 0.f};

    // ---- K loop: 16 steps of BK=32, double-buffered, 1 barrier/step ----
    int cur = 0;
    for (int ks = 0; ks < 16; ++ks) {
        if (ks < 15) {
            pa = *(const float4*)(asrc + (ks + 1) * 32);
            pb = *(const float4*)(asrc + (ks + 1) * 32 + 4);
            stageB(cur ^ 1, (ks + 1) * 32);
        }
        bf16x8 af0, af1;
        {
            int r0 = wm + c16;
            af0 = *(const bf16x8*)&As[cur][(r0 * 4 + (Q ^ ((r0 >> 1) & 3))) * 8];
            int r1 = wm + 16 + c16;
            af1 = *(const bf16x8*)&As[cur][(r1 * 4 + (Q ^ ((r1 >> 1) & 3))) * 8];
        }
        #pragma unroll
        for (int j = 0; j < 10; ++j) {
            int n = wn + j * 16 + c16;
            bf16x8 bv = *(const bf16x8*)&Bs[cur][(n * 4 + (Q ^ ((n >> 1) & 3))) * 8];
            acc[j]      = __builtin_amdgcn_mfma_f32_16x16x32_bf16(af0, bv, acc[j], 0, 0, 0);
            acc[10 + j] = __builtin_amdgcn_mfma_f32_16x16x32_bf16(af1, bv, acc[10 + j], 0, 0, 0);
        }
        if (ks < 15) writeA(cur ^ 1, pa, pb);
        __syncthreads();
        cur ^= 1;
    }

    // ---- bias ----
    #pragma unroll
    for (int j = 0; j < 10; ++j) {
        float bb = bias[g * Vn + wn + j * 16 + c16];
        acc[j][0] += bb; acc[j][1] += bb; acc[j][2] += bb; acc[j][3] += bb;
        acc[10+j][0] += bb; acc[10+j][1] += bb; acc[10+j][2] += bb; acc[10+j][3] += bb;
    }

    const float MARGIN = 0.0625f;

    // ---- phase 1: per-row half-stats + candidate pool ----
    #pragma unroll
    for (int i = 0; i < 2; ++i) {
        #pragma unroll
        for (int qr = 0; qr < 4; ++qr) {
            int row = wm + i * 16 + Q * 4 + qr;
            size_t r2 = (t0 + row) * 2 + g;
            const float* gr = gum + r2 * Vn + wn;
            float sv[10];
            float mxl = -1e30f, mxs = -1e30f; int bi = 0;
            #pragma unroll
            for (int j = 0; j < 10; ++j) {
                float lg = acc[i * 10 + j][qr];
                float gu = gr[j * 16 + c16];
                float s = lg + gu; sv[j] = s;
                mxl = fmaxf(mxl, lg);
                if (s > mxs) { mxs = s; bi = wn + j * 16 + c16; }
            }
            #pragma unroll
            for (int off = 1; off < 16; off <<= 1) {
                mxl = fmaxf(mxl, __shfl_xor(mxl, off));
                float os = __shfl_xor(mxs, off); int ob = __shfl_xor(bi, off);
                if (os > mxs || (os == mxs && ob < bi)) { mxs = os; bi = ob; }
            }
            float sum = 0.f;
            #pragma unroll
            for (int j = 0; j < 10; ++j) sum += __expf(acc[i * 10 + j][qr] - mxl);
            #pragma unroll
            for (int off = 1; off < 16; off <<= 1) sum += __shfl_xor(sum, off);

            float thr = mxs - MARGIN;
            #pragma unroll
            for (int j = 0; j < 10; ++j) {
                if (sv[j] >= thr) {
                    int pos = atomicAdd(&s_cnt[row], 1);
                    if (pos < 8) {
                        s_col[row][pos] = wn + j * 16 + c16;
                        s_s[row][pos]   = sv[j];
                        s_gm[row][pos]  = sv[j] - acc[i * 10 + j][qr];
                    }
                }
            }
            if (c16 == 0)
                part[row][half] = (float4){mxl, sum, mxs, __int_as_float(bi)};
        }
    }
    __syncthreads();

    // ---- phase 2: combine halves, write dist, final approx argmax ----
    #pragma unroll
    for (int i = 0; i < 2; ++i) {
        #pragma unroll
        for (int qr = 0; qr < 4; ++qr) {
            int row = wm + i * 16 + Q * 4 + qr;
            size_t r2 = (t0 + row) * 2 + g;
            float4 mine = part[row][half];
            float4 oth  = part[row][half ^ 1];
            float mxl_f = fmaxf(mine.x, oth.x);
            float sum_f = mine.y * __expf(mine.x - mxl_f) + oth.y * __expf(oth.x - mxl_f);
            float inv = 1.0f / sum_f;
            float* dr = dist + r2 * Vn + wn;
            #pragma unroll
            for (int j = 0; j < 10; ++j)
                dr[j * 16 + c16] = __expf(acc[i * 10 + j][qr] - mxl_f) * inv;
            if (half == 0 && c16 == 0) {
                float ms = mine.z; int mi = __float_as_int(mine.w);
                float os = oth.z;  int oi = __float_as_int(oth.w);
                if (os > ms || (os == ms && oi < mi)) { ms = os; mi = oi; }
                s_mxs[row] = ms; s_bidx[row] = mi;
            }
        }
    }
    __syncthreads();

    // ---- fixup: exact fp32 recompute for near-tie rows (16 units/wave) ----
    for (int u16i = 0; u16i < 16; ++u16i) {
        int u = w * 16 + u16i;
        int c = s_cnt[u]; if (c > 8) c = 8;
        float thr = s_mxs[u] - MARGIN;
        int nf = 0;
        for (int j = 0; j < c; ++j) nf += (s_s[u][j] >= thr) ? 1 : 0;
        if (nf > 1) {
            size_t t = t0 + u;
            const float* hr = hs + t * DIMK;
            float4 h0 = *(const float4*)(hr + lane * 8);
            float4 h1 = *(const float4*)(hr + lane * 8 + 4);
            float hv[8] = {h0.x, h0.y, h0.z, h0.w, h1.x, h1.y, h1.z, h1.w};
            float best = -1e30f; int bv2 = 1 << 30;
            for (int j = 0; j < c; ++j) {
                if (s_s[u][j] < thr) continue;
                int v = s_col[u][j];
                int gcol = g * Vn + v;
                const float* wc = W + gcol;
                float p = 0.f;
                #pragma unroll
                for (int i = 0; i < 8; ++i)
                    p = fmaf(hv[i], wc[(size_t)(lane * 8 + i) * GV], p);
                #pragma unroll
                for (int off = 1; off < 64; off <<= 1) p += __shfl_xor(p, off);
                float se = p + bias[gcol] + s_gm[u][j];
                if (se > best || (se == best && v < bv2)) { best = se; bv2 = v; }
            }
            if (lane == 0) s_bidx[u] = bv2;
        }
    }
    __syncthreads();

    // ---- gather codevectors -> out ----
    for (int u16i = 0; u16i < 16; ++u16i) {
        int u = w * 16 + u16i;
        size_t t = t0 + u;
        int b = s_bidx[u];
        const float2* cvr = (const float2*)(cv + ((size_t)(g * Vn + b)) * Dn);
        float2 val = cvr[lane];
        *(float2*)(out + t * (Gn * Dn) + g * Dn + lane * 2) = val;
    }
}

extern "C" void kernel_launch(void* const* d_in, const int* in_sizes, int n_in,
                              void* d_out, int out_size, void* d_ws, size_t ws_size,
                              hipStream_t stream) {
    const float* hs  = (const float*)d_in[0];  // [8,4096,512]
    const float* W   = (const float*)d_in[1];  // [512,640]
    const float* b   = (const float*)d_in[2];  // [640]
    const float* cv  = (const float*)d_in[3];  // [640,128]
    const float* gum = (const float*)d_in[4];  // [65536,320]

    float* out  = (float*)d_out;                      // [32768, 256]
    float* dist = out + (size_t)Tcnt * (Gn * Dn);     // [65536, 320]
    ushort* Wt  = (ushort*)d_ws;                      // [640, 512] bf16 = 640 KB

    prep_wt<<<80, 256, 0, stream>>>(W, Wt);
    fused_vq_kernel<<<512, 512, 0, stream>>>(hs, Wt, W, b, gum, cv, out, dist);
}

// Round 6
// 95.803 us; speedup vs baseline: 1.3992x; 1.3992x over previous
//
#include <hip/hip_runtime.h>

#define Tcnt 32768      // B*S
#define Gn   2
#define Vn   320
#define Dn   128
#define DIMK 512
#define GV   640        // G*V
#define RB   64         // rows per fused block

typedef __attribute__((ext_vector_type(8))) short bf16x8;
typedef __attribute__((ext_vector_type(4))) ushort u16x4;
typedef __attribute__((ext_vector_type(4))) float f32x4;

__device__ inline ushort f2bf(float x) {
    unsigned u = __float_as_uint(x);
    return (ushort)((u + 0x7fffu + ((u >> 16) & 1u)) >> 16);   // RNE
}

#define AS1(p) ((const __attribute__((address_space(1))) void*)(p))
#define AS3(p) ((__attribute__((address_space(3))) void*)(p))

// ---------------- prep: W [512,640] fp32 -> Wt [640,512] bf16 (transposed) ----------
__global__ __launch_bounds__(256) void prep_wt(
    const float* __restrict__ W, ushort* __restrict__ Wt)
{
    __shared__ ushort Ls[64][72];
    int t = blockIdx.x;                     // 0..79
    int n0 = (t % 10) * 64, k0 = (t / 10) * 64;
    int ln = threadIdx.x & 63, kq = threadIdx.x >> 6;
    #pragma unroll
    for (int kk = 0; kk < 16; ++kk) {
        int k = kq * 16 + kk;
        Ls[k][ln] = f2bf(W[(size_t)(k0 + k) * GV + n0 + ln]);
    }
    __syncthreads();
    #pragma unroll
    for (int nn = 0; nn < 16; ++nn) {
        int n = kq * 16 + nn;
        Wt[(size_t)(n0 + n) * DIMK + k0 + ln] = Ls[ln][n];
    }
}

// ------- fused: GEMM(64x320) + bias + softmax + gumbel-argmax(+fixup) + gather ------
__global__ __launch_bounds__(512, 4) void fused_vq_kernel(
    const float*  __restrict__ hs,    // [T, 512] fp32
    const ushort* __restrict__ Wt,    // [640, 512] bf16 transposed
    const float*  __restrict__ W,     // [512, 640] fp32 (fixup only)
    const float*  __restrict__ bias,  // [640]
    const float*  __restrict__ gum,   // [T*G, 320]
    const float*  __restrict__ cv,    // [640, 128]
    float* __restrict__ out,          // [T, 256]
    float* __restrict__ dist)         // [T*G, 320]
{
    __shared__ ushort As[2][RB * 32];     // 4 KB x2
    __shared__ ushort Bs[2][Vn * 32];     // 20 KB x2
    __shared__ float4 part[RB][2];        // {mxl, sum, mxs, idx} per half
    __shared__ int    s_cnt[RB];
    __shared__ int    s_col[RB][8];
    __shared__ float  s_s[RB][8];
    __shared__ float  s_gm[RB][8];
    __shared__ int    s_bidx[RB];
    __shared__ float  s_mxs[RB];

    const int tid = threadIdx.x, w = tid >> 6, lane = tid & 63;
    const int Q = lane >> 4, c16 = lane & 15;
    const int wm = (w >> 1) * 16, wn = (w & 1) * 160, half = w & 1;

    const int bid = blockIdx.x;
    const int swz = (bid & 7) * 128 + (bid >> 3);   // XCD chunking (1024 % 8 == 0)
    const int g = swz & 1;                          // (t,g0),(t,g1) adjacent on same XCD
    const size_t t0 = (size_t)(swz >> 1) * RB;

    if (tid < RB) s_cnt[tid] = 0;

    // ---- A staging map: thread -> (row, phys 4-float chunk); source pre-swizzled ----
    const int arow_s = tid >> 3, pc = tid & 7;
    const int lq = (pc >> 1) ^ ((arow_s >> 1) & 3);
    const int lc = lq * 2 + (pc & 1);
    const float* asrc = hs + (t0 + arow_s) * DIMK + lc * 4;
    const ushort* wtg = Wt + (size_t)g * Vn * DIMK;

    auto stageB = [&](int buf, int k0) {
        #pragma unroll
        for (int i2 = 0; i2 < 2; ++i2) {
            int s = i2 * 512 + tid;
            int n = s >> 2, pq = s & 3, lqq = pq ^ ((n >> 1) & 3);
            __builtin_amdgcn_global_load_lds(
                AS1(wtg + (size_t)n * DIMK + k0 + lqq * 8),
                AS3(&Bs[buf][s * 8]), 16, 0, 0);
        }
        if (w < 4) {
            int s = 1024 + tid;
            int n = s >> 2, pq = s & 3, lqq = pq ^ ((n >> 1) & 3);
            __builtin_amdgcn_global_load_lds(
                AS1(wtg + (size_t)n * DIMK + k0 + lqq * 8),
                AS3(&Bs[buf][s * 8]), 16, 0, 0);
        }
    };
    auto writeA = [&](int buf, float4 v) {
        u16x4 o;
        o[0] = f2bf(v.x); o[1] = f2bf(v.y); o[2] = f2bf(v.z); o[3] = f2bf(v.w);
        *(u16x4*)&As[buf][tid * 4] = o;
    };

    // ---- prologue: stage step 0, prefetch step 1 into regs ----
    float4 areg0 = *(const float4*)(asrc);
    stageB(0, 0);
    float4 areg1 = *(const float4*)(asrc + 32);
    writeA(0, areg0);
    __syncthreads();

    f32x4 acc[10];
    #pragma unroll
    for (int j = 0; j < 10; ++j) acc[j] = (f32x4){0.f, 0.f, 0.f, 0.f};

    // ---- K loop: 16 steps BK=32, dbuf B (gll), depth-2 A reg prefetch ----
    #pragma unroll
    for (int ks = 0; ks < 16; ++ks) {
        if (ks + 2 < 16) {
            if ((ks & 1) == 0) areg0 = *(const float4*)(asrc + (ks + 2) * 32);
            else               areg1 = *(const float4*)(asrc + (ks + 2) * 32);
        }
        if (ks + 1 < 16) stageB((ks + 1) & 1, (ks + 1) * 32);

        const ushort* Ab = As[ks & 1];
        const ushort* Bb = Bs[ks & 1];
        const int ar = wm + c16;
        bf16x8 af = *(const bf16x8*)&Ab[(ar * 4 + (Q ^ ((ar >> 1) & 3))) * 8];
        #pragma unroll
        for (int j = 0; j < 10; ++j) {
            int n = wn + j * 16 + c16;
            bf16x8 bv = *(const bf16x8*)&Bb[(n * 4 + (Q ^ ((n >> 1) & 3))) * 8];
            acc[j] = __builtin_amdgcn_mfma_f32_16x16x32_bf16(af, bv, acc[j], 0, 0, 0);
        }
        if (ks + 1 < 16) writeA((ks + 1) & 1, ((ks + 1) & 1) ? areg1 : areg0);
        __syncthreads();
    }

    // ---- bias ----
    #pragma unroll
    for (int j = 0; j < 10; ++j) {
        float bb = bias[g * Vn + wn + j * 16 + c16];
        acc[j][0] += bb; acc[j][1] += bb; acc[j][2] += bb; acc[j][3] += bb;
    }

    const float MARGIN = 0.0625f;

    // ---- phase 1: per-row half-stats + candidate pool ----
    #pragma unroll
    for (int qr = 0; qr < 4; ++qr) {
        int row = wm + Q * 4 + qr;                 // local row (C/D layout)
        size_t r2 = (t0 + row) * 2 + g;
        const float* gr = gum + r2 * Vn + wn;
        float sv[10];
        float mxl = -1e30f, mxs = -1e30f; int bi = 0;
        #pragma unroll
        for (int j = 0; j < 10; ++j) {
            float lg = acc[j][qr];
            float gu = gr[j * 16 + c16];
            float s = lg + gu; sv[j] = s;
            mxl = fmaxf(mxl, lg);
            if (s > mxs) { mxs = s; bi = wn + j * 16 + c16; }
        }
        #pragma unroll
        for (int off = 1; off < 16; off <<= 1) {
            mxl = fmaxf(mxl, __shfl_xor(mxl, off));
            float os = __shfl_xor(mxs, off); int ob = __shfl_xor(bi, off);
            if (os > mxs || (os == mxs && ob < bi)) { mxs = os; bi = ob; }
        }
        float sum = 0.f;
        #pragma unroll
        for (int j = 0; j < 10; ++j) sum += __expf(acc[j][qr] - mxl);
        #pragma unroll
        for (int off = 1; off < 16; off <<= 1) sum += __shfl_xor(sum, off);

        float thr = mxs - MARGIN;
        #pragma unroll
        for (int j = 0; j < 10; ++j) {
            if (sv[j] >= thr) {
                int pos = atomicAdd(&s_cnt[row], 1);
                if (pos < 8) {
                    s_col[row][pos] = wn + j * 16 + c16;
                    s_s[row][pos]   = sv[j];
                    s_gm[row][pos]  = sv[j] - acc[j][qr];
                }
            }
        }
        if (c16 == 0)
            part[row][half] = (float4){mxl, sum, mxs, __int_as_float(bi)};
    }
    __syncthreads();

    // ---- phase 2: combine halves, write dist, final approx argmax ----
    #pragma unroll
    for (int qr = 0; qr < 4; ++qr) {
        int row = wm + Q * 4 + qr;
        size_t r2 = (t0 + row) * 2 + g;
        float4 mine = part[row][half];
        float4 oth  = part[row][half ^ 1];
        float mxl_f = fmaxf(mine.x, oth.x);
        float sum_f = mine.y * __expf(mine.x - mxl_f) + oth.y * __expf(oth.x - mxl_f);
        float inv = 1.0f / sum_f;
        float* dr = dist + r2 * Vn + wn;
        #pragma unroll
        for (int j = 0; j < 10; ++j)
            dr[j * 16 + c16] = __expf(acc[j][qr] - mxl_f) * inv;
        if (half == 0 && c16 == 0) {
            float ms = mine.z; int mi = __float_as_int(mine.w);
            float os = oth.z;  int oi = __float_as_int(oth.w);
            if (os > ms || (os == ms && oi < mi)) { ms = os; mi = oi; }
            s_mxs[row] = ms; s_bidx[row] = mi;
        }
    }
    __syncthreads();

    // ---- fixup: exact fp32 recompute for near-tie rows (8 units/wave) ----
    for (int ui = 0; ui < 8; ++ui) {
        int u = w * 8 + ui;
        int c = s_cnt[u]; if (c > 8) c = 8;
        float thr = s_mxs[u] - MARGIN;
        int nf = 0;
        for (int j = 0; j < c; ++j) nf += (s_s[u][j] >= thr) ? 1 : 0;
        if (nf > 1) {
            size_t t = t0 + u;
            const float* hr = hs + t * DIMK;
            float4 h0 = *(const float4*)(hr + lane * 8);
            float4 h1 = *(const float4*)(hr + lane * 8 + 4);
            float hv[8] = {h0.x, h0.y, h0.z, h0.w, h1.x, h1.y, h1.z, h1.w};
            float best = -1e30f; int bv2 = 1 << 30;
            for (int j = 0; j < c; ++j) {
                if (s_s[u][j] < thr) continue;
                int v = s_col[u][j];
                int gcol = g * Vn + v;
                const float* wc = W + gcol;
                float p = 0.f;
                #pragma unroll
                for (int i = 0; i < 8; ++i)
                    p = fmaf(hv[i], wc[(size_t)(lane * 8 + i) * GV], p);
                #pragma unroll
                for (int off = 1; off < 64; off <<= 1) p += __shfl_xor(p, off);
                float se = p + bias[gcol] + s_gm[u][j];
                if (se > best || (se == best && v < bv2)) { best = se; bv2 = v; }
            }
            if (lane == 0) s_bidx[u] = bv2;
        }
    }
    __syncthreads();

    // ---- gather codevectors -> out ----
    for (int ui = 0; ui < 8; ++ui) {
        int u = w * 8 + ui;
        size_t t = t0 + u;
        int b = s_bidx[u];
        const float2* cvr = (const float2*)(cv + ((size_t)(g * Vn + b)) * Dn);
        float2 val = cvr[lane];
        *(float2*)(out + t * (Gn * Dn) + g * Dn + lane * 2) = val;
    }
}

extern "C" void kernel_launch(void* const* d_in, const int* in_sizes, int n_in,
                              void* d_out, int out_size, void* d_ws, size_t ws_size,
                              hipStream_t stream) {
    const float* hs  = (const float*)d_in[0];  // [8,4096,512]
    const float* W   = (const float*)d_in[1];  // [512,640]
    const float* b   = (const float*)d_in[2];  // [640]
    const float* cv  = (const float*)d_in[3];  // [640,128]
    const float* gum = (const float*)d_in[4];  // [65536,320]

    float* out  = (float*)d_out;                      // [32768, 256]
    float* dist = out + (size_t)Tcnt * (Gn * Dn);     // [65536, 320]
    ushort* Wt  = (ushort*)d_ws;                      // [640, 512] bf16 = 640 KB

    prep_wt<<<80, 256, 0, stream>>>(W, Wt);
    fused_vq_kernel<<<(Tcnt / RB) * Gn, 512, 0, stream>>>(hs, Wt, W, b, gum, cv, out, dist);
}